// Round 1
// baseline (2798.463 us; speedup 1.0000x reference)
//
#include <hip/hip_runtime.h>

#define N_NODES 100000
#define N_EDGES 1600000
#define D_IN    128
#define D_OUT   256

// ---------------------------------------------------------------------------
// Detect whether edge_index was materialized as int64 or int32.
// Values are in [0, 100000). If stored int64 (little-endian), every odd int32
// word is a zero high-word. If int32, 16 consecutive odd positions being all
// zero has probability ~1e-80. One thread writes a flag into d_ws.
// ---------------------------------------------------------------------------
__global__ void detect_idx64_kernel(const int* __restrict__ edge32,
                                    int* __restrict__ flag) {
    if (threadIdx.x == 0 && blockIdx.x == 0) {
        int is64 = 1;
        for (int i = 1; i < 32; i += 2) {
            if (edge32[i] != 0) { is64 = 0; break; }
        }
        *flag = is64;
    }
}

// ---------------------------------------------------------------------------
// Scatter: acc[dst] += H[src] for each edge. One thread per (edge, 4 channels)
// -> E*32 threads. Lanes 0..31 of a pair share an edge; float4 read of H row
// is coalesced across the 32 lanes; 4 f32 atomics into acc.
// ---------------------------------------------------------------------------
__global__ __launch_bounds__(256) void scatter_kernel(
        const float* __restrict__ H,
        const void*  __restrict__ edge_raw,
        const int*   __restrict__ flag,
        float* __restrict__ acc) {
    long long tid = (long long)blockIdx.x * blockDim.x + threadIdx.x;
    if (tid >= (long long)N_EDGES * 32) return;
    int e  = (int)(tid >> 5);
    int c4 = ((int)tid & 31) << 2;

    int src, dst;
    if (*flag) {
        const long long* e64 = (const long long*)edge_raw;
        src = (int)e64[e];
        dst = (int)e64[(long long)N_EDGES + e];
    } else {
        const int* e32 = (const int*)edge_raw;
        src = e32[e];
        dst = e32[N_EDGES + e];
    }
    if ((unsigned)src >= N_NODES || (unsigned)dst >= N_NODES) return;

    const float4 v = *reinterpret_cast<const float4*>(
        H + (long long)src * D_IN + c4);
    float* p = acc + (long long)dst * D_IN + c4;
    atomicAdd(p + 0, v.x);
    atomicAdd(p + 1, v.y);
    atomicAdd(p + 2, v.z);
    atomicAdd(p + 3, v.w);
}

// ---------------------------------------------------------------------------
// out = relu((H + acc) @ W).  Tile: 64 rows x 256 cols per 256-thread block.
// X tile staged in LDS [64][128] f32 (32 KiB). Thread (ty=tid/64, tx=tid%64)
// computes rows ty*16..+15, cols tx*4..+3 (16x4 f32 accumulators).
// LDS reads are wave-uniform (broadcast, conflict-free); W reads are
// contiguous 1KiB per wave per k-step (L1/L2-resident, 128KiB total).
// ---------------------------------------------------------------------------
__global__ __launch_bounds__(256) void gemm_relu_kernel(
        const float* __restrict__ H,
        const float* __restrict__ acc,
        const float* __restrict__ Wm,
        float* __restrict__ out) {
    __shared__ float Xs[64][D_IN];

    const int g   = blockIdx.x * 64;   // base row of this block
    const int tid = threadIdx.x;

    // ---- load X = H + acc : 8192 floats, 32 per thread (8 x float4) ----
    {
        const int kidx = tid & 31;        // k-group: covers k = kidx*4..+3
        const int rg   = tid >> 5;        // row group 0..7
        #pragma unroll
        for (int j = 0; j < 8; ++j) {
            const int r = rg + j * 8;
            const long long row = g + r;
            float4 x = make_float4(0.f, 0.f, 0.f, 0.f);
            if (row < N_NODES) {
                const float4 h = *reinterpret_cast<const float4*>(
                    H + row * D_IN + kidx * 4);
                const float4 a = *reinterpret_cast<const float4*>(
                    acc + row * D_IN + kidx * 4);
                x = make_float4(h.x + a.x, h.y + a.y, h.z + a.z, h.w + a.w);
            }
            *reinterpret_cast<float4*>(&Xs[r][kidx * 4]) = x;
        }
    }
    __syncthreads();

    const int ty = tid >> 6;   // 0..3  -> rows ty*16..+15
    const int tx = tid & 63;   // 0..63 -> cols tx*4..+3

    float accv[16][4];
    #pragma unroll
    for (int r = 0; r < 16; ++r)
        #pragma unroll
        for (int j = 0; j < 4; ++j) accv[r][j] = 0.f;

    const float* Wp = Wm + tx * 4;

    #pragma unroll 2
    for (int k = 0; k < D_IN; k += 4) {
        const float4 w0 = *reinterpret_cast<const float4*>(Wp + (k + 0) * D_OUT);
        const float4 w1 = *reinterpret_cast<const float4*>(Wp + (k + 1) * D_OUT);
        const float4 w2 = *reinterpret_cast<const float4*>(Wp + (k + 2) * D_OUT);
        const float4 w3 = *reinterpret_cast<const float4*>(Wp + (k + 3) * D_OUT);
        #pragma unroll
        for (int r = 0; r < 16; ++r) {
            const float4 x = *reinterpret_cast<const float4*>(&Xs[ty * 16 + r][k]);
            accv[r][0] = fmaf(x.x, w0.x, accv[r][0]);
            accv[r][0] = fmaf(x.y, w1.x, accv[r][0]);
            accv[r][0] = fmaf(x.z, w2.x, accv[r][0]);
            accv[r][0] = fmaf(x.w, w3.x, accv[r][0]);

            accv[r][1] = fmaf(x.x, w0.y, accv[r][1]);
            accv[r][1] = fmaf(x.y, w1.y, accv[r][1]);
            accv[r][1] = fmaf(x.z, w2.y, accv[r][1]);
            accv[r][1] = fmaf(x.w, w3.y, accv[r][1]);

            accv[r][2] = fmaf(x.x, w0.z, accv[r][2]);
            accv[r][2] = fmaf(x.y, w1.z, accv[r][2]);
            accv[r][2] = fmaf(x.z, w2.z, accv[r][2]);
            accv[r][2] = fmaf(x.w, w3.z, accv[r][2]);

            accv[r][3] = fmaf(x.x, w0.w, accv[r][3]);
            accv[r][3] = fmaf(x.y, w1.w, accv[r][3]);
            accv[r][3] = fmaf(x.z, w2.w, accv[r][3]);
            accv[r][3] = fmaf(x.w, w3.w, accv[r][3]);
        }
    }

    // ---- relu + store (coalesced float4 per row) ----
    #pragma unroll
    for (int r = 0; r < 16; ++r) {
        const long long row = (long long)g + ty * 16 + r;
        if (row < N_NODES) {
            float4 o;
            o.x = fmaxf(accv[r][0], 0.f);
            o.y = fmaxf(accv[r][1], 0.f);
            o.z = fmaxf(accv[r][2], 0.f);
            o.w = fmaxf(accv[r][3], 0.f);
            *reinterpret_cast<float4*>(out + row * D_OUT + tx * 4) = o;
        }
    }
}

extern "C" void kernel_launch(void* const* d_in, const int* in_sizes, int n_in,
                              void* d_out, int out_size, void* d_ws, size_t ws_size,
                              hipStream_t stream) {
    const float* H    = (const float*)d_in[0];
    const void*  edge = d_in[1];
    const float* Wm   = (const float*)d_in[2];
    float* out = (float*)d_out;

    const size_t acc_bytes = (size_t)N_NODES * D_IN * sizeof(float);
    float* acc  = (float*)d_ws;
    int*   flag = (int*)((char*)d_ws + acc_bytes);

    // zero the accumulator every call (harness poisons ws once, never re-poisons)
    hipMemsetAsync(d_ws, 0, acc_bytes, stream);

    detect_idx64_kernel<<<1, 64, 0, stream>>>((const int*)edge, flag);

    const long long scatter_threads = (long long)N_EDGES * 32;
    const int scatter_blocks = (int)((scatter_threads + 255) / 256);
    scatter_kernel<<<scatter_blocks, 256, 0, stream>>>(H, edge, flag, acc);

    const int gemm_blocks = (N_NODES + 63) / 64;
    gemm_relu_kernel<<<gemm_blocks, 256, 0, stream>>>(H, acc, Wm, out);
}

// Round 2
// 463.448 us; speedup vs baseline: 6.0383x; 6.0383x over previous
//
#include <hip/hip_runtime.h>

#define N_NODES 100000
#define N_EDGES 1600000
#define D_IN    128
#define D_OUT   256
#define NB_SCAN ((N_NODES + 255) / 256)   // 391 blocks for node-indexed scans

// ---------------------------------------------------------------------------
// Detect whether edge_index was materialized as int64 or int32.
// Values are in [0, 100000). If int64 (LE), every odd int32 word is zero.
// ---------------------------------------------------------------------------
__global__ void detect_idx64_kernel(const int* __restrict__ edge32,
                                    int* __restrict__ flag) {
    if (threadIdx.x == 0 && blockIdx.x == 0) {
        int is64 = 1;
        for (int i = 1; i < 32; i += 2) {
            if (edge32[i] != 0) { is64 = 0; break; }
        }
        *flag = is64;
    }
}

__device__ __forceinline__ int load_dst(const void* edge_raw, int is64, int e) {
    if (is64) return (int)((const long long*)edge_raw)[(long long)N_EDGES + e];
    return ((const int*)edge_raw)[N_EDGES + e];
}
__device__ __forceinline__ int load_src(const void* edge_raw, int is64, int e) {
    if (is64) return (int)((const long long*)edge_raw)[e];
    return ((const int*)edge_raw)[e];
}

// ---------------------------------------------------------------------------
// 1) histogram of destinations into counts[] (int atomics, L2/mem-side, cheap)
// ---------------------------------------------------------------------------
__global__ __launch_bounds__(256) void hist_kernel(
        const void* __restrict__ edge_raw, const int* __restrict__ flag,
        int* __restrict__ counts) {
    int e = blockIdx.x * blockDim.x + threadIdx.x;
    if (e >= N_EDGES) return;
    int dst = load_dst(edge_raw, *flag, e);
    if ((unsigned)dst < N_NODES) atomicAdd(&counts[dst], 1);
}

// ---------------------------------------------------------------------------
// 2a) per-256-block sums of counts -> bsum[NB_SCAN]
// ---------------------------------------------------------------------------
__global__ __launch_bounds__(256) void block_sum_kernel(
        const int* __restrict__ counts, int* __restrict__ bsum) {
    __shared__ int lds[256];
    int t = threadIdx.x;
    int i = blockIdx.x * 256 + t;
    lds[t] = (i < N_NODES) ? counts[i] : 0;
    __syncthreads();
    for (int off = 128; off > 0; off >>= 1) {
        if (t < off) lds[t] += lds[t + off];
        __syncthreads();
    }
    if (t == 0) bsum[blockIdx.x] = lds[0];
}

// ---------------------------------------------------------------------------
// 2b) exclusive scan of bsum (391 elems) in one 512-thread block.
//     Also writes row_start[N_NODES] = N_EDGES (total is compile-time).
// ---------------------------------------------------------------------------
__global__ __launch_bounds__(512) void scan_bsum_kernel(
        int* __restrict__ bsum, int* __restrict__ row_start) {
    __shared__ int lds[512];
    int t = threadIdx.x;
    lds[t] = (t < NB_SCAN) ? bsum[t] : 0;
    __syncthreads();
    for (int off = 1; off < 512; off <<= 1) {
        int u = (t >= off) ? lds[t - off] : 0;
        __syncthreads();
        lds[t] += u;
        __syncthreads();
    }
    int excl = (t == 0) ? 0 : lds[t - 1];
    if (t < NB_SCAN) bsum[t] = excl;
    if (t == 0) row_start[N_NODES] = N_EDGES;
}

// ---------------------------------------------------------------------------
// 2c) per-element exclusive scan: row_start[i] = bsum[b] + excl_scan(counts).
//     counts_cursor is read as counts then overwritten with the cursor copy.
// ---------------------------------------------------------------------------
__global__ __launch_bounds__(256) void scan_counts_kernel(
        int* __restrict__ counts_cursor, const int* __restrict__ bsum,
        int* __restrict__ row_start) {
    __shared__ int lds[256];
    int t = threadIdx.x;
    int i = blockIdx.x * 256 + t;
    int c = (i < N_NODES) ? counts_cursor[i] : 0;
    lds[t] = c;
    __syncthreads();
    for (int off = 1; off < 256; off <<= 1) {
        int u = (t >= off) ? lds[t - off] : 0;
        __syncthreads();
        lds[t] += u;
        __syncthreads();
    }
    int rs = bsum[blockIdx.x] + lds[t] - c;   // exclusive
    if (i < N_NODES) {
        row_start[i] = rs;
        counts_cursor[i] = rs;                // cursor starts at row_start
    }
}

// ---------------------------------------------------------------------------
// 3) fill CSR: csr_src[pos] = src, pos = cursor[dst]++
// ---------------------------------------------------------------------------
__global__ __launch_bounds__(256) void fill_kernel(
        const void* __restrict__ edge_raw, const int* __restrict__ flag,
        int* __restrict__ cursor, int* __restrict__ csr_src) {
    int e = blockIdx.x * blockDim.x + threadIdx.x;
    if (e >= N_EDGES) return;
    int is64 = *flag;
    int src = load_src(edge_raw, is64, e);
    int dst = load_dst(edge_raw, is64, e);
    if ((unsigned)dst >= N_NODES || (unsigned)src >= N_NODES) return;
    int pos = atomicAdd(&cursor[dst], 1);
    csr_src[pos] = src;
}

// ---------------------------------------------------------------------------
// 4) fused: X[row] = H[row] + sum_{s in nbrs(row)} H[s]  (gather, no atomics)
//    then out = relu(X @ W).  64 rows x 256 cols per 256-thread block.
//    Gather: wave w handles local rows w*16..w*16+15; lane holds 2 channels
//    (float2); one coalesced 512B read per neighbor, L3-resident.
// ---------------------------------------------------------------------------
__global__ __launch_bounds__(256) void gather_gemm_relu_kernel(
        const float* __restrict__ H,
        const int* __restrict__ row_start,
        const int* __restrict__ csr_src,
        const float* __restrict__ Wm,
        float* __restrict__ out) {
    __shared__ float Xs[64][D_IN];

    const int g    = blockIdx.x * 64;
    const int tid  = threadIdx.x;
    const int wv   = tid >> 6;
    const int lane = tid & 63;

    // ---- gather phase ----
    #pragma unroll 1
    for (int jj = 0; jj < 16; ++jj) {
        const int r   = wv * 16 + jj;
        const int row = g + r;
        float2 s = make_float2(0.f, 0.f);
        if (row < N_NODES) {
            s = *((const float2*)(H + (long long)row * D_IN) + lane);
            const int start = row_start[row];
            const int end   = row_start[row + 1];
            for (int base = start; base < end; base += 64) {
                int m = end - base;
                if (m > 64) m = 64;
                int idx = 0;
                if (lane < m) idx = csr_src[base + lane];
                int n = 0;
                for (; n + 4 <= m; n += 4) {
                    const int i0 = __shfl(idx, n);
                    const int i1 = __shfl(idx, n + 1);
                    const int i2 = __shfl(idx, n + 2);
                    const int i3 = __shfl(idx, n + 3);
                    const float2 v0 = ((const float2*)(H + (long long)i0 * D_IN))[lane];
                    const float2 v1 = ((const float2*)(H + (long long)i1 * D_IN))[lane];
                    const float2 v2 = ((const float2*)(H + (long long)i2 * D_IN))[lane];
                    const float2 v3 = ((const float2*)(H + (long long)i3 * D_IN))[lane];
                    s.x += v0.x; s.y += v0.y;
                    s.x += v1.x; s.y += v1.y;
                    s.x += v2.x; s.y += v2.y;
                    s.x += v3.x; s.y += v3.y;
                }
                for (; n < m; ++n) {
                    const int i0 = __shfl(idx, n);
                    const float2 v = ((const float2*)(H + (long long)i0 * D_IN))[lane];
                    s.x += v.x; s.y += v.y;
                }
            }
        }
        *((float2*)&Xs[r][lane * 2]) = s;
    }
    __syncthreads();

    // ---- GEMM + ReLU phase ----
    const int ty = tid >> 6;   // 0..3  -> rows ty*16..+15
    const int tx = tid & 63;   // 0..63 -> cols tx*4..+3

    float accv[16][4];
    #pragma unroll
    for (int r = 0; r < 16; ++r)
        #pragma unroll
        for (int j = 0; j < 4; ++j) accv[r][j] = 0.f;

    const float* Wp = Wm + tx * 4;

    #pragma unroll 2
    for (int k = 0; k < D_IN; k += 4) {
        const float4 w0 = *reinterpret_cast<const float4*>(Wp + (k + 0) * D_OUT);
        const float4 w1 = *reinterpret_cast<const float4*>(Wp + (k + 1) * D_OUT);
        const float4 w2 = *reinterpret_cast<const float4*>(Wp + (k + 2) * D_OUT);
        const float4 w3 = *reinterpret_cast<const float4*>(Wp + (k + 3) * D_OUT);
        #pragma unroll
        for (int r = 0; r < 16; ++r) {
            const float4 x = *reinterpret_cast<const float4*>(&Xs[ty * 16 + r][k]);
            accv[r][0] = fmaf(x.x, w0.x, accv[r][0]);
            accv[r][0] = fmaf(x.y, w1.x, accv[r][0]);
            accv[r][0] = fmaf(x.z, w2.x, accv[r][0]);
            accv[r][0] = fmaf(x.w, w3.x, accv[r][0]);

            accv[r][1] = fmaf(x.x, w0.y, accv[r][1]);
            accv[r][1] = fmaf(x.y, w1.y, accv[r][1]);
            accv[r][1] = fmaf(x.z, w2.y, accv[r][1]);
            accv[r][1] = fmaf(x.w, w3.y, accv[r][1]);

            accv[r][2] = fmaf(x.x, w0.z, accv[r][2]);
            accv[r][2] = fmaf(x.y, w1.z, accv[r][2]);
            accv[r][2] = fmaf(x.z, w2.z, accv[r][2]);
            accv[r][2] = fmaf(x.w, w3.z, accv[r][2]);

            accv[r][3] = fmaf(x.x, w0.w, accv[r][3]);
            accv[r][3] = fmaf(x.y, w1.w, accv[r][3]);
            accv[r][3] = fmaf(x.z, w2.w, accv[r][3]);
            accv[r][3] = fmaf(x.w, w3.w, accv[r][3]);
        }
    }

    #pragma unroll
    for (int r = 0; r < 16; ++r) {
        const int row = g + ty * 16 + r;
        if (row < N_NODES) {
            float4 o;
            o.x = fmaxf(accv[r][0], 0.f);
            o.y = fmaxf(accv[r][1], 0.f);
            o.z = fmaxf(accv[r][2], 0.f);
            o.w = fmaxf(accv[r][3], 0.f);
            *reinterpret_cast<float4*>(out + (long long)row * D_OUT + tx * 4) = o;
        }
    }
}

extern "C" void kernel_launch(void* const* d_in, const int* in_sizes, int n_in,
                              void* d_out, int out_size, void* d_ws, size_t ws_size,
                              hipStream_t stream) {
    const float* H    = (const float*)d_in[0];
    const void*  edge = d_in[1];
    const float* Wm   = (const float*)d_in[2];
    float* out = (float*)d_out;

    // workspace layout (all 16B-aligned):
    const size_t off_rs   = 0;                                        // (N+1) ints
    const size_t off_cur  = ((size_t)(N_NODES + 1) * 4 + 15) & ~(size_t)15;  // 400016
    const size_t off_csr  = off_cur + (size_t)N_NODES * 4;            // 800016
    const size_t off_bsum = off_csr + (size_t)N_EDGES * 4;            // 7200016
    const size_t off_flag = off_bsum + (((size_t)NB_SCAN * 4 + 15) & ~(size_t)15);

    int* row_start = (int*)((char*)d_ws + off_rs);
    int* cursor    = (int*)((char*)d_ws + off_cur);   // doubles as counts
    int* csr_src   = (int*)((char*)d_ws + off_csr);
    int* bsum      = (int*)((char*)d_ws + off_bsum);
    int* flag      = (int*)((char*)d_ws + off_flag);

    detect_idx64_kernel<<<1, 64, 0, stream>>>((const int*)edge, flag);

    hipMemsetAsync(cursor, 0, (size_t)N_NODES * 4, stream);

    const int edge_blocks = (N_EDGES + 255) / 256;
    hist_kernel<<<edge_blocks, 256, 0, stream>>>(edge, flag, cursor);
    block_sum_kernel<<<NB_SCAN, 256, 0, stream>>>(cursor, bsum);
    scan_bsum_kernel<<<1, 512, 0, stream>>>(bsum, row_start);
    scan_counts_kernel<<<NB_SCAN, 256, 0, stream>>>(cursor, bsum, row_start);
    fill_kernel<<<edge_blocks, 256, 0, stream>>>(edge, flag, cursor, csr_src);

    const int gemm_blocks = (N_NODES + 63) / 64;
    gather_gemm_relu_kernel<<<gemm_blocks, 256, 0, stream>>>(
        H, row_start, csr_src, Wm, out);
}